// Round 13
// baseline (264.901 us; speedup 1.0000x reference)
//
#include <hip/hip_runtime.h>
#include <hip/hip_bf16.h>

#define T_LEN 1024
#define NH    16
#define CH    64
#define LSTR  64        // Q-prologue LDS row stride in shorts (128 B)
#define FSTR  520       // fragment stride in shorts (512 + 8 pad)
#define VOFF  (8 * FSTR)   // one K-or-V tile buffer in shorts (4160)

typedef __attribute__((ext_vector_type(8))) short short8;
typedef __attribute__((ext_vector_type(4))) float floatx4;
typedef unsigned long long u64;

__device__ __forceinline__ short f2bf(float x) {
    __hip_bfloat16 b = __float2bfloat16(x);   // RNE (prologue-only scalar path)
    return *(short*)&b;
}
__device__ __forceinline__ unsigned cvt_pk_bf16(float lo, float hi) {
    unsigned r;
    asm("v_cvt_pk_bf16_f32 %0, %1, %2" : "=v"(r) : "v"(lo), "v"(hi));
    return r;
}
// XOR block-swizzle for the Q prologue tile (stride-64-short rows).
__device__ __forceinline__ int fsw(int row) {
    return (((row & 7) ^ ((row >> 3) & 7)) << 3);
}
// In-half K-row permutation for the pair-split scheme: QK output block sb,
// slot (q,r) must hold logical s = 8q + 4sb + r so the K=32 PV A-frag
// assembles in-register.  Logical s (0..31) -> physical row:
// [p4 p3 p2 p1 p0] = [s2 s4 s3 s1 s0]  (bit permutation => bijective).
__device__ __forceinline__ int kperm32(int s) {
    return ((s & 4) << 2) | ((s & 0x18) >> 1) | (s & 3);
}
// Block-placement XOR-fold (r9): frag reads + b128 writes conflict-free.
__device__ __forceinline__ int bfold(int bi) {
    return bi ^ ((bi >> 3) & 7);
}

// ---- mask bit-pack: (8,1024,1024) int32 -> (8,1024,16) u64 via wave ballot ----
__global__ __launch_bounds__(256)
void pack_mask_kernel(const int* __restrict__ mask, u64* __restrict__ pm)
{
    const int NW = 8 * T_LEN * (T_LEN / 64);   // 131072 words
    const int lane = threadIdx.x & 63;
    const int gw = (int)((blockIdx.x * blockDim.x + threadIdx.x) >> 6);
    const int nw = (int)((gridDim.x * blockDim.x) >> 6);
    for (int w0 = gw; w0 < NW; w0 += 4 * nw) {
        int v[4];
        #pragma unroll
        for (int i = 0; i < 4; ++i) {
            const int w = w0 + i * nw;
            v[i] = (w < NW) ? mask[(size_t)w * 64 + lane] : 0;
        }
        #pragma unroll
        for (int i = 0; i < 4; ++i) {
            const int w = w0 + i * nw;
            const u64 bb = __ballot(v[i] != 0);
            if (lane == 0 && w < NW) pm[w] = bb;
        }
    }
}

// QK+softmax of this wave's s-half of one tile -> PV A-frags (both t-blocks)
// in registers.  MA/MB are the wave's u32 mask halves for rows tlA/tlB.
#define QK_TILE(TILE, KC, MA, MB, PA_, PB_) do {                              \
    _Pragma("unroll")                                                         \
    for (int sb = 0; sb < 2; ++sb) {                                          \
        const short8 bk0 = *(const short8*)&(KC)[(sh4 + sb)     * FSTR + bsl8]; \
        const short8 bk1 = *(const short8*)&(KC)[(sh4 + 2 + sb) * FSTR + bsl8]; \
        floatx4 accA = (floatx4){b_l2e, b_l2e, b_l2e, b_l2e};                 \
        floatx4 accB = (floatx4){b_l2e, b_l2e, b_l2e, b_l2e};                 \
        accA = __builtin_amdgcn_mfma_f32_16x16x32_bf16(bk0, aq00, accA, 0,0,0); \
        accA = __builtin_amdgcn_mfma_f32_16x16x32_bf16(bk1, aq01, accA, 0,0,0); \
        accB = __builtin_amdgcn_mfma_f32_16x16x32_bf16(bk0, aq10, accB, 0,0,0); \
        accB = __builtin_amdgcn_mfma_f32_16x16x32_bf16(bk1, aq11, accB, 0,0,0); \
        const int sbb = 8 * quad + 4 * sb;      /* s within the 32-half */    \
        unsigned msA = 0, msB = 0;                                            \
        if (PM) { msA = ((MA) >> sbb) & 0xFu; msB = ((MB) >> sbb) & 0xFu; }   \
        float fA[4], fB[4];                                                   \
        _Pragma("unroll")                                                     \
        for (int r = 0; r < 4; ++r) {                                         \
            bool keepA, keepB;                                                \
            if (PM) { keepA = ((msA >> r) & 1u) != 0;                         \
                      keepB = ((msB >> r) & 1u) != 0; }                       \
            else    { const int sg = (TILE)*64 + sh*32 + sbb + r;             \
                      keepA = mrowA[sg] != 0; keepB = mrowB[sg] != 0; }       \
            const float eA = __builtin_amdgcn_exp2f(accA[r]);                 \
            const float eB = __builtin_amdgcn_exp2f(accB[r]);                 \
            fA[r] = keepA ? eA : 0.f;  fB[r] = keepB ? eB : 0.f;              \
        }                                                                     \
        (PA_)[sb*2+0] = cvt_pk_bf16(fA[0], fA[1]);                            \
        (PA_)[sb*2+1] = cvt_pk_bf16(fA[2], fA[3]);                            \
        (PB_)[sb*2+0] = cvt_pk_bf16(fB[0], fB[1]);                            \
        (PB_)[sb*2+1] = cvt_pk_bf16(fB[2], fB[3]);                            \
    }                                                                         \
} while (0)

// Partial PV over this wave's s-half (K=32 MFMAs), both t-blocks.
#define PV_TILE(VC, PA_, PB_) do {                                            \
    const short8 apA = *(const short8*)&(PA_)[0];                             \
    const short8 apB = *(const short8*)&(PB_)[0];                             \
    __builtin_amdgcn_s_setprio(1);                                            \
    _Pragma("unroll")                                                         \
    for (int cb = 0; cb < 4; ++cb) {                                          \
        const short8 bv = *(const short8*)&(VC)[(sh4 + cb) * FSTR + bsl8];    \
        o[0][cb] = __builtin_amdgcn_mfma_f32_16x16x32_bf16(apA, bv, o[0][cb],0,0,0); \
        o[1][cb] = __builtin_amdgcn_mfma_f32_16x16x32_bf16(apB, bv, o[1][cb],0,0,0); \
    }                                                                         \
    ol[0] = __builtin_amdgcn_mfma_f32_16x16x32_bf16(apA, ones8, ol[0], 0,0,0); \
    ol[1] = __builtin_amdgcn_mfma_f32_16x16x32_bf16(apB, ones8, ol[1], 0,0,0); \
    __builtin_amdgcn_s_setprio(0);                                            \
} while (0)

// K tile: 8 transposed coalesced dword loads (one frag block per thread).
#define K_LOAD(DST, S0) do {                                                  \
    _Pragma("unroll")                                                         \
    for (int j = 0; j < 8; ++j) (DST)[j] = kpK[j * T_LEN + (S0)];             \
} while (0)
#define K_WRITE(KD, R) do {                                                   \
    uint4 kw_;                                                                \
    kw_.x = cvt_pk_bf16((R)[0], (R)[1]);                                      \
    kw_.y = cvt_pk_bf16((R)[2], (R)[3]);                                      \
    kw_.z = cvt_pk_bf16((R)[4], (R)[5]);                                      \
    kw_.w = cvt_pk_bf16((R)[6], (R)[7]);                                      \
    *(uint4*)&(KD)[kwadrK] = kw_;                                             \
} while (0)
#define V_WRITE(VD, B0, B1) do {                                              \
    uint4 vw_;                                                                \
    vw_.x = cvt_pk_bf16((B0).x, (B0).y);                                      \
    vw_.y = cvt_pk_bf16((B0).z, (B0).w);                                      \
    vw_.z = cvt_pk_bf16((B1).x, (B1).y);                                      \
    vw_.w = cvt_pk_bf16((B1).z, (B1).w);                                      \
    *(uint4*)&(VD)[vwadr] = vw_;                                              \
} while (0)

// One block = 8 waves = 512 threads: one (head-batch, 128-row Q tile).
// PAIR-SPLIT: 8 waves = 4 row-groups (32 t-rows) x 2 s-halves.  Each wave
// computes QK (full c=64) for its 32 rows x its 32-s half and accumulates
// PARTIAL PV over that half -> K/V LDS reads per wave-window halve
// (8 b128 vs 16) at UNCHANGED wave count and MFMA count (the LDS broadcast
// was the top pipe at ~44%; r4/r10 showed cutting wave count loses more).
// Pair partials summed once in a 2-pass LDS epilogue.  Chassis = r11:
// cross-tile pipeline {QK(s+1) || PV(s) || stage(s+2)}, K x2 / V x3
// buffers, kperm32'd fragment-major K, bfold placement, packed u32 masks.
// launch_bounds (512,2) -> 128-VGPR cap (est ~120). Spill tripwire: FETCH.
template<bool PM>
__global__ __launch_bounds__(512, 2)
void qkv_attn_kernel(const float* __restrict__ qkv,
                     const int* __restrict__ mask,
                     const u64* __restrict__ pm,
                     const float* __restrict__ qk_bias,
                     float* __restrict__ out)
{
    // 42112 B = 5 tile buffers x 4160 shorts (K0|K1|V0|V1|V2) + 512 B Ol.
    // prologue: shorts 0..8191 = Q [128][LSTR] swizzled (overlaps K0|K1).
    // epilogue: Os fp32 [128][64] = 32 KB + Ol[128] beyond the buffers.
    __shared__ __align__(16) char smem[5 * VOFF * 2 + 512];
    short* Qs = (short*)smem;
    short* const Kb[2] = { Qs,            Qs + VOFF };
    short* const Vb[3] = { Qs + 2 * VOFF, Qs + 3 * VOFF, Qs + 4 * VOFF };
    float* Os = (float*)smem;
    float* Ol = (float*)(smem + 5 * VOFF * 2);   // 128 row-sums (pass 1)

    const int tid  = threadIdx.x;
    const int wave = tid >> 6;
    const int lane = tid & 63;
    const int quad = lane >> 4;
    const int l16  = lane & 15;
    const int rg   = wave & 3;          // row-group: t rows rg*32..rg*32+31
    const int sh   = wave >> 2;         // s-half: s sh*32..sh*32+31 per tile
    const int sh4  = sh * 4;            // frag base for this half

    const int bh    = blockIdx.x;   // 0..127: consecutive bh -> XCD round-robin
    const int qtile = blockIdx.y;   // 0..7:  stride-128 ids keep a bh on ONE XCD
    const int b     = bh >> 4;
    const int h     = bh & 15;
    const int t0    = qtile * 128;

    const size_t qbase = ((size_t)b * (3 * NH * CH) + (size_t)h * (3 * CH)) * T_LEN;
    const float* kp = qkv + qbase + (size_t)CH * T_LEN;
    const float* vp = qkv + qbase + (size_t)(2 * CH) * T_LEN;

    const float b_l2e  = qk_bias[0] * 1.44269504088896f;  // exp(x)=exp2(x*log2e)
    const float qscale = 0.125f * 1.44269504088896f;      // folded into Q staging

    const int c64 = tid >> 3;          // 0..63 channel row (Q/V staging)
    const int sse = (tid & 7) * 8;     // 8-s segment per thread (V staging)
    const int tse = (tid & 7) * 16;    // Q staging segment

    // K loader: wave w <-> channels 8w..8w+7, lane <-> s.  One frag block.
    const float* kpK = kp + (size_t)(wave * 8) * T_LEN + lane;
    {
    }
    const int k32  = kperm32(lane & 31);
    const int kwadrK = ((lane >> 5) * 4 + (wave >> 2) * 2 + (k32 >> 4)) * FSTR
                     + bfold((wave & 3) * 16 + (k32 & 15)) * 8;

    // V loader: frag f = (s-half)*4 + c-block; block = s-quad*16 + c-low.
    const float* vpr = vp + (size_t)c64 * T_LEN + sse;
    const int vwadr = ((sse >> 5) * 4 + (c64 >> 4)) * FSTR
                    + bfold(((sse >> 3) & 3) * 16 + (c64 & 15)) * 8;

    // fragment-read base: folded block of this lane (reads are lane=block).
    const int bsl8 = bfold(lane) * 8;

    // Masks: lane's two t rows; only this wave's u32 half of each word.
    const int tlA = t0 + rg * 32 + l16;
    const int tlB = tlA + 16;
    const unsigned* pmhA = PM ?
        (const unsigned*)(pm + ((size_t)(h & 7) * T_LEN + tlA) * (T_LEN / 64)) + sh : nullptr;
    const unsigned* pmhB = PM ?
        (const unsigned*)(pm + ((size_t)(h & 7) * T_LEN + tlB) * (T_LEN / 64)) + sh : nullptr;
    const int* mrowA = mask + (size_t)(h & 7) * T_LEN * T_LEN + (size_t)tlA * T_LEN;
    const int* mrowB = mrowA + 16 * T_LEN;

    // ---- prologue loads: K0,K1 (transposed), V0,V1, mask halves ----
    float kr[8], kr1[8];
    K_LOAD(kr, 0);
    K_LOAD(kr1, 64);
    float4 vf0 = *(const float4*)(vpr);
    float4 vf1 = *(const float4*)(vpr + 4);
    float4 vg0 = *(const float4*)(vpr + 64);
    float4 vg1 = *(const float4*)(vpr + 68);
    unsigned m0A = PM ? pmhA[0] : 0u,  m0B = PM ? pmhB[0] : 0u;
    unsigned mnA = PM ? pmhA[2] : 0u,  mnB = PM ? pmhB[2] : 0u;

    // ---- stage Q transposed + swizzled + PRE-SCALED (shorts 0..8191) ----
    {
        const float* src = qkv + qbase + (size_t)c64 * T_LEN + t0 + tse;
        #pragma unroll
        for (int k = 0; k < 4; ++k) {
            float4 f = *(const float4*)(src + 4 * k);
            const int t = tse + 4 * k;
            Qs[(t + 0) * LSTR + (c64 ^ fsw(t + 0))] = f2bf(f.x * qscale);
            Qs[(t + 1) * LSTR + (c64 ^ fsw(t + 1))] = f2bf(f.y * qscale);
            Qs[(t + 2) * LSTR + (c64 ^ fsw(t + 2))] = f2bf(f.z * qscale);
            Qs[(t + 3) * LSTR + (c64 ^ fsw(t + 3))] = f2bf(f.w * qscale);
        }
    }
    __syncthreads();

    // ---- loop-invariant Q fragments: both t-blocks of the row-group ----
    const int qrA = rg * 32 + l16;
    const int qrB = qrA + 16;
    const short8 aq00 = *(const short8*)&Qs[qrA * LSTR + ((quad * 8)      ^ fsw(qrA))];
    const short8 aq01 = *(const short8*)&Qs[qrA * LSTR + ((quad * 8 + 32) ^ fsw(qrA))];
    const short8 aq10 = *(const short8*)&Qs[qrB * LSTR + ((quad * 8)      ^ fsw(qrB))];
    const short8 aq11 = *(const short8*)&Qs[qrB * LSTR + ((quad * 8 + 32) ^ fsw(qrB))];
    __syncthreads();   // Q region reused by K0/K1 below

    // ---- stage K0,K1,V0,V1 ----
    K_WRITE(Kb[0], kr);
    K_WRITE(Kb[1], kr1);
    V_WRITE(Vb[0], vf0, vf1);
    V_WRITE(Vb[1], vg0, vg1);
    __syncthreads();

    const short one_bf = (short)0x3F80;
    const short8 ones8 = (short8){one_bf, one_bf, one_bf, one_bf,
                                  one_bf, one_bf, one_bf, one_bf};

    floatx4 o[2][4], ol[2];
    #pragma unroll
    for (int t = 0; t < 2; ++t) {
        #pragma unroll
        for (int i = 0; i < 4; ++i) o[t][i] = (floatx4){0.f, 0.f, 0.f, 0.f};
        ol[t] = (floatx4){0.f, 0.f, 0.f, 0.f};
    }

    // ---- pipeline prime: QK(0); barrier before window 0 overwrites K0 ----
    unsigned paq[2][2][4] __attribute__((aligned(16)));
    QK_TILE(0, Kb[0], m0A, m0B, paq[0][0], paq[0][1]);
    __syncthreads();

    // ---- steady: {QK(s+1) || PV(s) || stage K(s+2), V(s+2)}; 1 barrier ----
    #pragma unroll
    for (int s = 0; s < 15; ++s) {
        if (s <= 13) {
            K_LOAD(kr, (s + 2) * 64);
            vf0 = *(const float4*)(vpr + (s + 2) * 64);
            vf1 = *(const float4*)(vpr + (s + 2) * 64 + 4);
        }
        const unsigned muA = mnA, muB = mnB;       // mask halves for tile s+1
        if (PM && s <= 13) { mnA = pmhA[2 * (s + 2)]; mnB = pmhB[2 * (s + 2)]; }

        QK_TILE(s + 1, Kb[(s + 1) & 1], muA, muB,
                paq[(s + 1) & 1][0], paq[(s + 1) & 1][1]);
        PV_TILE(Vb[s % 3], paq[s & 1][0], paq[s & 1][1]);

        if (s <= 13) {
            K_WRITE(Kb[s & 1], kr);                // K(s+2)
            V_WRITE(Vb[(s + 2) % 3], vf0, vf1);    // V(s+2)
        }
        __syncthreads();
    }
    PV_TILE(Vb[15 % 3], paq[1][0], paq[1][1]);     // drain: PV(15)

    // ---- epilogue: pair reduction + normalize + coalesced store ----
    __syncthreads();   // all compute done before Os overwrites buffers
    // pass 1: s-half 0 writes raw partials (O and row-sums)
    if (sh == 0) {
        #pragma unroll
        for (int tb = 0; tb < 2; ++tb) {
            const int key = ((rg * 2 + tb) << 3) ^ (quad << 4);
            #pragma unroll
            for (int cb = 0; cb < 4; ++cb)
                #pragma unroll
                for (int r = 0; r < 4; ++r)
                    Os[(rg * 32 + tb * 16 + quad * 4 + r) * 64
                       + ((cb * 16 + l16) ^ key)] = o[tb][cb][r];
            if (l16 == 0)
                #pragma unroll
                for (int r = 0; r < 4; ++r)
                    Ol[rg * 32 + tb * 16 + quad * 4 + r] = ol[tb][r];
        }
    }
    __syncthreads();
    // pass 2: s-half 1 adds its partials, normalizes, writes final
    if (sh == 1) {
        #pragma unroll
        for (int tb = 0; tb < 2; ++tb) {
            const int key = ((rg * 2 + tb) << 3) ^ (quad << 4);
            float inv[4];
            #pragma unroll
            for (int r = 0; r < 4; ++r) {
                const float lt = ol[tb][r] + Ol[rg * 32 + tb * 16 + quad * 4 + r];
                inv[r] = (lt > 0.f) ? 1.f / lt : 0.f;
            }
            #pragma unroll
            for (int cb = 0; cb < 4; ++cb)
                #pragma unroll
                for (int r = 0; r < 4; ++r) {
                    const int idx = (rg * 32 + tb * 16 + quad * 4 + r) * 64
                                  + ((cb * 16 + l16) ^ key);
                    Os[idx] = (Os[idx] + o[tb][cb][r]) * inv[r];
                }
        }
    }
    __syncthreads();
    {
        float* dst = out + ((size_t)b * (NH * CH) + (size_t)h * CH + c64) * T_LEN
                   + t0 + tse;
        #pragma unroll
        for (int k = 0; k < 4; ++k) {
            float4 f;
            #pragma unroll
            for (int j = 0; j < 4; ++j) {
                const int rl = tse + 4 * k + j;
                const int ok = ((rl >> 4) << 3) ^ (((rl >> 2) & 3) << 4);
                ((float*)&f)[j] = Os[rl * 64 + (c64 ^ ok)];
            }
            *(float4*)(dst + 4 * k) = f;
        }
    }
}

extern "C" void kernel_launch(void* const* d_in, const int* in_sizes, int n_in,
                              void* d_out, int out_size, void* d_ws, size_t ws_size,
                              hipStream_t stream) {
    const float* qkv     = (const float*)d_in[0];
    const int*   mask    = (const int*)d_in[1];
    const float* qk_bias = (const float*)d_in[2];
    float*       out     = (float*)d_out;

    const size_t pm_bytes = (size_t)8 * T_LEN * (T_LEN / 64) * sizeof(u64);  // 1 MiB
    u64* pm = nullptr;
    if (d_ws && ws_size >= pm_bytes) {
        pm = (u64*)d_ws;
        pack_mask_kernel<<<2048, 256, 0, stream>>>(mask, pm);
    }

    dim3 grid(8 * NH, T_LEN / 128);  // (head-batches, q-tiles) = (128, 8)
    if (pm) qkv_attn_kernel<true ><<<grid, 512, 0, stream>>>(qkv, mask, pm, qk_bias, out);
    else    qkv_attn_kernel<false><<<grid, 512, 0, stream>>>(qkv, mask, nullptr, qk_bias, out);
}

// Round 14
// 239.128 us; speedup vs baseline: 1.1078x; 1.1078x over previous
//
#include <hip/hip_runtime.h>
#include <hip/hip_bf16.h>

#define T_LEN 1024
#define NH    16
#define CH    64
#define LSTR  64        // Q-prologue LDS row stride in shorts (128 B)
#define FSTR  520       // fragment stride in shorts (512 + 8 pad)
#define VOFF  (8 * FSTR)   // one K-or-V buffer in shorts (4160 = 8320 B)

typedef __attribute__((ext_vector_type(8))) short short8;
typedef __attribute__((ext_vector_type(4))) float floatx4;
typedef unsigned long long u64;

__device__ __forceinline__ short f2bf(float x) {
    __hip_bfloat16 b = __float2bfloat16(x);   // RNE (prologue-only scalar path)
    return *(short*)&b;
}
// HW packed conversion: dst.lo16 = bf16(lo), dst.hi16 = bf16(hi).
__device__ __forceinline__ unsigned cvt_pk_bf16(float lo, float hi) {
    unsigned r;
    asm("v_cvt_pk_bf16_f32 %0, %1, %2" : "=v"(r) : "v"(lo), "v"(hi));
    return r;
}
// XOR block-swizzle for the Q prologue tile (stride-64-short rows).
__device__ __forceinline__ int fsw(int row) {
    return (((row & 7) ^ ((row >> 3) & 7)) << 3);
}
// K-row permutation (r6+): physical s-row kperm(s) makes the swapped
// QK^T output land so the PV A-frag assembles in-register.
__device__ __forceinline__ int kperm(int s) {
    return (s & 0x23) | ((s & 0x18) >> 1) | ((s & 4) << 2);
}
// Block-placement XOR-fold (r9): frag reads + b128 writes conflict-free.
__device__ __forceinline__ int bfold(int bi) {
    return bi ^ ((bi >> 3) & 7);
}

// ---- mask bit-pack: (8,1024,1024) int32 -> (8,1024,16) u64 via wave ballot ----
__global__ __launch_bounds__(256)
void pack_mask_kernel(const int* __restrict__ mask, u64* __restrict__ pm)
{
    const int NW = 8 * T_LEN * (T_LEN / 64);   // 131072 words
    const int lane = threadIdx.x & 63;
    const int gw = (int)((blockIdx.x * blockDim.x + threadIdx.x) >> 6);
    const int nw = (int)((gridDim.x * blockDim.x) >> 6);
    for (int w0 = gw; w0 < NW; w0 += 4 * nw) {
        int v[4];
        #pragma unroll
        for (int i = 0; i < 4; ++i) {
            const int w = w0 + i * nw;
            v[i] = (w < NW) ? mask[(size_t)w * 64 + lane] : 0;
        }
        #pragma unroll
        for (int i = 0; i < 4; ++i) {
            const int w = w0 + i * nw;
            const u64 bb = __ballot(v[i] != 0);
            if (lane == 0 && w < NW) pm[w] = bb;
        }
    }
}

// QK+softmax of one tile -> P fragment in registers (r9's body).
#define QK_TILE(TILE, KC, MW, PDST) do {                                      \
    _Pragma("unroll")                                                         \
    for (int sub = 0; sub < 4; ++sub) {                                       \
        const short8 bk0 = *(const short8*)&(KC)[(sub*2+0)*FSTR + bsl8];      \
        const short8 bk1 = *(const short8*)&(KC)[(sub*2+1)*FSTR + bsl8];      \
        floatx4 acc = (floatx4){b_l2e, b_l2e, b_l2e, b_l2e};                  \
        acc = __builtin_amdgcn_mfma_f32_16x16x32_bf16(bk0, aq0, acc, 0,0,0);  \
        acc = __builtin_amdgcn_mfma_f32_16x16x32_bf16(bk1, aq1, acc, 0,0,0);  \
        const int sbase = 32*(sub>>1) + 4*(sub&1) + 8*quad;                   \
        unsigned mseg = 0;                                                    \
        if (PM) mseg = (unsigned)((MW) >> sbase) & 0xFu;                      \
        float pf[4];                                                          \
        _Pragma("unroll")                                                     \
        for (int r = 0; r < 4; ++r) {                                         \
            bool keep;                                                        \
            if (PM) keep = ((mseg >> r) & 1u) != 0;                           \
            else    keep = mrow[(TILE)*64 + sbase + r] != 0;                  \
            const float e = __builtin_amdgcn_exp2f(acc[r]);                   \
            pf[r] = keep ? e : 0.f;                                           \
        }                                                                     \
        (PDST)[sub*2+0] = cvt_pk_bf16(pf[0], pf[1]);                          \
        (PDST)[sub*2+1] = cvt_pk_bf16(pf[2], pf[3]);                          \
    }                                                                         \
} while (0)

// PV accumulate of one tile from a register P fragment.
#define PV_TILE(VC, PSRC) do {                                                \
    const short8 ap0 = *(const short8*)&(PSRC)[0];                            \
    const short8 ap1 = *(const short8*)&(PSRC)[4];                            \
    __builtin_amdgcn_s_setprio(1);                                            \
    _Pragma("unroll")                                                         \
    for (int csub = 0; csub < 4; ++csub) {                                    \
        const short8 bv0 = *(const short8*)&(VC)[(csub*2+0)*FSTR + bsl8];     \
        const short8 bv1 = *(const short8*)&(VC)[(csub*2+1)*FSTR + bsl8];     \
        o[csub] = __builtin_amdgcn_mfma_f32_16x16x32_bf16(ap0, bv0, o[csub],0,0,0); \
        o[csub] = __builtin_amdgcn_mfma_f32_16x16x32_bf16(ap1, bv1, o[csub],0,0,0); \
    }                                                                         \
    ol = __builtin_amdgcn_mfma_f32_16x16x32_bf16(ap0, ones8, ol, 0,0,0);      \
    ol = __builtin_amdgcn_mfma_f32_16x16x32_bf16(ap1, ones8, ol, 0,0,0);      \
    __builtin_amdgcn_s_setprio(0);                                            \
} while (0)

// K tile: 8 transposed coalesced dword loads (transpose paid on the global
// side; each load instr is 64 consecutive s x 4 B = fully coalesced) so the
// LDS write is ONE b128 at the thread's fragment block (was 8 scattered b16).
#define K_LOAD(DST, S0) do {                                                  \
    _Pragma("unroll")                                                         \
    for (int j = 0; j < 8; ++j) (DST)[j] = kpK[j * T_LEN + (S0)];             \
} while (0)
#define K_WRITE(KD, R) do {                                                   \
    uint4 kw_;                                                                \
    kw_.x = cvt_pk_bf16((R)[0], (R)[1]);                                      \
    kw_.y = cvt_pk_bf16((R)[2], (R)[3]);                                      \
    kw_.z = cvt_pk_bf16((R)[4], (R)[5]);                                      \
    kw_.w = cvt_pk_bf16((R)[6], (R)[7]);                                      \
    *(uint4*)&(KD)[kwadrK] = kw_;                                             \
} while (0)
#define V_WRITE(VD, B0, B1) do {                                              \
    uint4 vw_;                                                                \
    vw_.x = cvt_pk_bf16((B0).x, (B0).y);                                      \
    vw_.y = cvt_pk_bf16((B0).z, (B0).w);                                      \
    vw_.z = cvt_pk_bf16((B1).x, (B1).y);                                      \
    vw_.w = cvt_pk_bf16((B1).z, (B1).w);                                      \
    *(uint4*)&(VD)[vwadr] = vw_;                                              \
} while (0)

// One block = 8 waves = 512 threads: one (head-batch, 128-row Q tile).
// == r11 (measured best, 92.1 us) + the ISOLATED good half of r12 ==
// Cross-tile pipeline: each barrier window runs
//   {QK+softmax(tile s+1) || PV(tile s) || stage K(s+2), V(s+2)}
// K double-buffered, V TRIPLE-buffered (keeps the staging prefetch a full
// 2 windows ahead — r12's tight V-dbuf ping-pong regressed, r13's
// pair-split regressed; this schedule at 16 q-rows/wave is the proven
// local optimum).  K staged via transposed GLOBAL loads -> one b128 LDS
// write per thread (r12-verified addressing; conflicts 2.7e6 -> 1.6e6).
// Swapped QK^T + kperm'd fragment-major K -> P entirely in registers;
// bfold'd block placement -> conflict-free frag reads; packed-bit mask;
// exp2 with pre-scaled Q and bias-in-C-init; ones-MFMA row sums.
// launch_bounds (512,2) -> 128-VGPR cap. Spill tripwire: FETCH balloon.
template<bool PM>
__global__ __launch_bounds__(512, 2)
void qkv_attn_kernel(const float* __restrict__ qkv,
                     const int* __restrict__ mask,
                     const u64* __restrict__ pm,
                     const float* __restrict__ qk_bias,
                     float* __restrict__ out)
{
    // 41600 B = 5 buffers x 4160 shorts: K0|K1|V0|V1|V2 (tile i -> K[i&1], V[i%3]).
    // prologue: shorts 0..8191 = Q [128][LSTR] swizzled (overlaps K0|K1).
    // epilogue: Os fp32 [128][64] = 32 KB (overlaps K0..V1).
    __shared__ __align__(16) char smem[5 * VOFF * 2];
    short* Qs = (short*)smem;
    short* const Kb[2] = { Qs,            Qs + VOFF };
    short* const Vb[3] = { Qs + 2 * VOFF, Qs + 3 * VOFF, Qs + 4 * VOFF };
    float* Os = (float*)smem;

    const int tid  = threadIdx.x;
    const int wave = tid >> 6;
    const int lane = tid & 63;
    const int quad = lane >> 4;
    const int l16  = lane & 15;

    const int bh    = blockIdx.x;   // 0..127: consecutive bh -> XCD round-robin
    const int qtile = blockIdx.y;   // 0..7:  stride-128 ids keep a bh on ONE XCD
    const int b     = bh >> 4;
    const int h     = bh & 15;
    const int t0    = qtile * 128;

    const size_t qbase = ((size_t)b * (3 * NH * CH) + (size_t)h * (3 * CH)) * T_LEN;
    const float* kp = qkv + qbase + (size_t)CH * T_LEN;
    const float* vp = qkv + qbase + (size_t)(2 * CH) * T_LEN;

    const float b_l2e  = qk_bias[0] * 1.44269504088896f;  // exp(x)=exp2(x*log2e)
    const float qscale = 0.125f * 1.44269504088896f;      // folded into Q staging

    const int c64 = tid >> 3;          // 0..63 channel row (Q/V staging)
    const int sse = (tid & 7) * 8;     // 8-s segment per thread (V staging)
    const int tse = (tid & 7) * 16;    // Q staging segment

    // K loader: wave w <-> channels 8w..8w+7, lane <-> s within the tile.
    const float* kpK = kp + (size_t)(wave * 8) * T_LEN + lane;
    const int spl = kperm(lane);
    const int kwadrK = ((spl >> 4) * 2 + (wave >> 2)) * FSTR
                     + bfold((wave & 3) * 16 + (spl & 15)) * 8;

    const float* vpr = vp + (size_t)c64 * T_LEN + sse;
    const int vwadr = ((c64 >> 4) * 2 + (sse >> 5)) * FSTR
                    + bfold(((sse >> 3) & 3) * 16 + (c64 & 15)) * 8;

    // fragment-read base (shorts): folded block of this lane, 16B-aligned
    const int bsl8 = bfold(lane) * 8;

    const int tl = t0 + wave * 16 + l16;   // lane's own t (mask row)
    const u64* pmb = PM ? pm + ((size_t)(h & 7) * T_LEN + tl) * (T_LEN / 64) : nullptr;
    const int* mrow = mask + (size_t)(h & 7) * T_LEN * T_LEN + (size_t)tl * T_LEN;

    // ---- prologue loads: K0,K1 (transposed dwords), V0,V1, masks ----
    float kr0[8], kr1[8];
    K_LOAD(kr0, 0);
    K_LOAD(kr1, 64);
    float4 vf0 = *(const float4*)(vpr);
    float4 vf1 = *(const float4*)(vpr + 4);
    float4 vg0 = *(const float4*)(vpr + 64);
    float4 vg1 = *(const float4*)(vpr + 68);
    u64 m0     = PM ? pmb[0] : 0ULL;
    u64 m_next = PM ? pmb[1] : 0ULL;

    // ---- stage Q transposed + swizzled + PRE-SCALED (shorts 0..8191) ----
    {
        const float* src = qkv + qbase + (size_t)c64 * T_LEN + t0 + tse;
        #pragma unroll
        for (int k = 0; k < 4; ++k) {
            float4 f = *(const float4*)(src + 4 * k);
            const int t = tse + 4 * k;
            Qs[(t + 0) * LSTR + (c64 ^ fsw(t + 0))] = f2bf(f.x * qscale);
            Qs[(t + 1) * LSTR + (c64 ^ fsw(t + 1))] = f2bf(f.y * qscale);
            Qs[(t + 2) * LSTR + (c64 ^ fsw(t + 2))] = f2bf(f.z * qscale);
            Qs[(t + 3) * LSTR + (c64 ^ fsw(t + 3))] = f2bf(f.w * qscale);
        }
    }
    __syncthreads();

    // ---- loop-invariant Q fragments (B-operand of swapped QK^T) ----
    const int qrow = wave * 16 + l16;
    const short8 aq0 = *(const short8*)&Qs[qrow * LSTR + ((quad * 8)      ^ fsw(qrow))];
    const short8 aq1 = *(const short8*)&Qs[qrow * LSTR + ((quad * 8 + 32) ^ fsw(qrow))];
    __syncthreads();   // Q region reused by K0/K1 below

    // ---- stage tiles 0,1 into K0/V0, K1/V1 ----
    K_WRITE(Kb[0], kr0);
    K_WRITE(Kb[1], kr1);
    V_WRITE(Vb[0], vf0, vf1);
    V_WRITE(Vb[1], vg0, vg1);
    __syncthreads();

    const short one_bf = (short)0x3F80;
    const short8 ones8 = (short8){one_bf, one_bf, one_bf, one_bf,
                                  one_bf, one_bf, one_bf, one_bf};

    floatx4 o[4], ol;
    #pragma unroll
    for (int i = 0; i < 4; ++i) o[i] = (floatx4){0.f, 0.f, 0.f, 0.f};
    ol = (floatx4){0.f, 0.f, 0.f, 0.f};

    // ---- pipeline prime: QK(0) -> pa[0]; barrier before window 0 writes K0 ----
    unsigned pa[2][8];
    QK_TILE(0, Kb[0], m0, pa[0]);
    __syncthreads();

    // ---- steady: {QK(s+1) || PV(s) || stage K(s+2), V(s+2)}; 1 barrier ----
    #pragma unroll
    for (int s = 0; s < 15; ++s) {
        if (s + 2 <= 15) {
            K_LOAD(kr0, (s + 2) * 64);                       // K(s+2) -> regs
            vf0 = *(const float4*)(vpr + (s + 2) * 64);      // V(s+2) -> regs
            vf1 = *(const float4*)(vpr + (s + 2) * 64 + 4);
        }
        const u64 m_use = m_next;                            // mask for tile s+1
        if (PM && s + 2 <= 15) m_next = pmb[s + 2];

        QK_TILE(s + 1, Kb[(s + 1) & 1], m_use, pa[(s + 1) & 1]);
        PV_TILE(Vb[s % 3], pa[s & 1]);

        if (s + 2 <= 15) {
            K_WRITE(Kb[s & 1], kr0);                         // K(s+2)
            V_WRITE(Vb[(s + 2) % 3], vf0, vf1);              // V(s+2)
        }
        __syncthreads();
    }
    PV_TILE(Vb[15 % 3], pa[15 & 1]);                         // drain: PV(15)

    // ---- epilogue: Os fp32 [128][64] (32 KB); double-XOR swizzle ----
    __syncthreads();   // all compute done before Os overwrites K/V buffers
    float inv[4];
    #pragma unroll
    for (int r = 0; r < 4; ++r) inv[r] = (ol[r] > 0.f) ? 1.f / ol[r] : 0.f;
    const int okeyw = (wave << 3) ^ (quad << 4);
    #pragma unroll
    for (int csub = 0; csub < 4; ++csub)
        #pragma unroll
        for (int r = 0; r < 4; ++r)
            Os[(wave * 16 + quad * 4 + r) * 64 + ((csub * 16 + l16) ^ okeyw)] =
                o[csub][r] * inv[r];
    __syncthreads();
    {
        float* dst = out + ((size_t)b * (NH * CH) + (size_t)h * CH + c64) * T_LEN
                   + t0 + tse;
        #pragma unroll
        for (int k = 0; k < 4; ++k) {
            float4 f;
            #pragma unroll
            for (int j = 0; j < 4; ++j) {
                const int rl = tse + 4 * k + j;
                const int ok = ((rl >> 4) << 3) ^ (((rl >> 2) & 3) << 4);
                ((float*)&f)[j] = Os[rl * 64 + (c64 ^ ok)];
            }
            *(float4*)(dst + 4 * k) = f;
        }
    }
}

extern "C" void kernel_launch(void* const* d_in, const int* in_sizes, int n_in,
                              void* d_out, int out_size, void* d_ws, size_t ws_size,
                              hipStream_t stream) {
    const float* qkv     = (const float*)d_in[0];
    const int*   mask    = (const int*)d_in[1];
    const float* qk_bias = (const float*)d_in[2];
    float*       out     = (float*)d_out;

    const size_t pm_bytes = (size_t)8 * T_LEN * (T_LEN / 64) * sizeof(u64);  // 1 MiB
    u64* pm = nullptr;
    if (d_ws && ws_size >= pm_bytes) {
        pm = (u64*)d_ws;
        pack_mask_kernel<<<2048, 256, 0, stream>>>(mask, pm);
    }

    dim3 grid(8 * NH, T_LEN / 128);  // (head-batches, q-tiles) = (128, 8)
    if (pm) qkv_attn_kernel<true ><<<grid, 512, 0, stream>>>(qkv, mask, pm, qk_bias, out);
    else    qkv_attn_kernel<false><<<grid, 512, 0, stream>>>(qkv, mask, nullptr, qk_bias, out);
}

// Round 15
// 228.215 us; speedup vs baseline: 1.1608x; 1.0478x over previous
//
#include <hip/hip_runtime.h>
#include <hip/hip_bf16.h>

#define T_LEN 1024
#define NH    16
#define CH    64
#define LSTR  64        // Q-prologue LDS row stride in shorts (128 B)
#define FSTR  520       // fragment stride in shorts (512 + 8 pad)
#define VOFF  (8 * FSTR)   // one K-or-V buffer in shorts (4160 = 8320 B)

typedef __attribute__((ext_vector_type(8))) short short8;
typedef __attribute__((ext_vector_type(4))) float floatx4;
typedef unsigned long long u64;

__device__ __forceinline__ short f2bf(float x) {
    __hip_bfloat16 b = __float2bfloat16(x);   // RNE (prologue-only scalar path)
    return *(short*)&b;
}
// HW packed conversion: dst.lo16 = bf16(lo), dst.hi16 = bf16(hi).
__device__ __forceinline__ unsigned cvt_pk_bf16(float lo, float hi) {
    unsigned r;
    asm("v_cvt_pk_bf16_f32 %0, %1, %2" : "=v"(r) : "v"(lo), "v"(hi));
    return r;
}
// XOR block-swizzle for the Q prologue tile (stride-64-short rows).
__device__ __forceinline__ int fsw(int row) {
    return (((row & 7) ^ ((row >> 3) & 7)) << 3);
}
// K-row permutation (r6+): physical s-row kperm(s) makes the swapped
// QK^T output land so the PV A-frag assembles in-register.
__device__ __forceinline__ int kperm(int s) {
    return (s & 0x23) | ((s & 0x18) >> 1) | ((s & 4) << 2);
}
// Block-placement XOR-fold (r9): frag reads + b128 writes conflict-free,
// K b16 writes 2-way (free).  Verified: conflicts 1.42e7 -> 2.7e6.
__device__ __forceinline__ int bfold(int bi) {
    return bi ^ ((bi >> 3) & 7);
}

// ---- mask bit-pack: (8,1024,1024) int32 -> (8,1024,16) u64 via wave ballot ----
__global__ __launch_bounds__(256)
void pack_mask_kernel(const int* __restrict__ mask, u64* __restrict__ pm)
{
    const int NW = 8 * T_LEN * (T_LEN / 64);   // 131072 words
    const int lane = threadIdx.x & 63;
    const int gw = (int)((blockIdx.x * blockDim.x + threadIdx.x) >> 6);
    const int nw = (int)((gridDim.x * blockDim.x) >> 6);
    for (int w0 = gw; w0 < NW; w0 += 4 * nw) {
        int v[4];
        #pragma unroll
        for (int i = 0; i < 4; ++i) {
            const int w = w0 + i * nw;
            v[i] = (w < NW) ? mask[(size_t)w * 64 + lane] : 0;
        }
        #pragma unroll
        for (int i = 0; i < 4; ++i) {
            const int w = w0 + i * nw;
            const u64 bb = __ballot(v[i] != 0);
            if (lane == 0 && w < NW) pm[w] = bb;
        }
    }
}

// QK+softmax of one tile -> P fragment in registers (r9's body).
#define QK_TILE(TILE, KC, MW, PDST) do {                                      \
    _Pragma("unroll")                                                         \
    for (int sub = 0; sub < 4; ++sub) {                                       \
        const short8 bk0 = *(const short8*)&(KC)[(sub*2+0)*FSTR + bsl8];      \
        const short8 bk1 = *(const short8*)&(KC)[(sub*2+1)*FSTR + bsl8];      \
        floatx4 acc = (floatx4){b_l2e, b_l2e, b_l2e, b_l2e};                  \
        acc = __builtin_amdgcn_mfma_f32_16x16x32_bf16(bk0, aq0, acc, 0,0,0);  \
        acc = __builtin_amdgcn_mfma_f32_16x16x32_bf16(bk1, aq1, acc, 0,0,0);  \
        const int sbase = 32*(sub>>1) + 4*(sub&1) + 8*quad;                   \
        unsigned mseg = 0;                                                    \
        if (PM) mseg = (unsigned)((MW) >> sbase) & 0xFu;                      \
        float pf[4];                                                          \
        _Pragma("unroll")                                                     \
        for (int r = 0; r < 4; ++r) {                                         \
            bool keep;                                                        \
            if (PM) keep = ((mseg >> r) & 1u) != 0;                           \
            else    keep = mrow[(TILE)*64 + sbase + r] != 0;                  \
            const float e = __builtin_amdgcn_exp2f(acc[r]);                   \
            pf[r] = keep ? e : 0.f;                                           \
        }                                                                     \
        (PDST)[sub*2+0] = cvt_pk_bf16(pf[0], pf[1]);                          \
        (PDST)[sub*2+1] = cvt_pk_bf16(pf[2], pf[3]);                          \
    }                                                                         \
} while (0)

// PV accumulate of one tile from a register P fragment.
#define PV_TILE(VC, PSRC) do {                                                \
    const short8 ap0 = *(const short8*)&(PSRC)[0];                            \
    const short8 ap1 = *(const short8*)&(PSRC)[4];                            \
    __builtin_amdgcn_s_setprio(1);                                            \
    _Pragma("unroll")                                                         \
    for (int csub = 0; csub < 4; ++csub) {                                    \
        const short8 bv0 = *(const short8*)&(VC)[(csub*2+0)*FSTR + bsl8];     \
        const short8 bv1 = *(const short8*)&(VC)[(csub*2+1)*FSTR + bsl8];     \
        o[csub] = __builtin_amdgcn_mfma_f32_16x16x32_bf16(ap0, bv0, o[csub],0,0,0); \
        o[csub] = __builtin_amdgcn_mfma_f32_16x16x32_bf16(ap1, bv1, o[csub],0,0,0); \
    }                                                                         \
    ol = __builtin_amdgcn_mfma_f32_16x16x32_bf16(ap0, ones8, ol, 0,0,0);      \
    ol = __builtin_amdgcn_mfma_f32_16x16x32_bf16(ap1, ones8, ol, 0,0,0);      \
    __builtin_amdgcn_s_setprio(0);                                            \
} while (0)

// cvt + LDS write of a staged K/V tile (fragment-major, folded).  K's
// transpose is paid as 8 b16 writes at loop-invariant precomputed addrs
// (coalesced float4 GLOBAL loads — r14 showed transposed global K loads
// regress via VMEM fragmentation: FETCH 115->131 MB, dur +11%).
#define KV_WRITE(KD, VD, A0, A1, B0, B1) do {                                 \
    const float kv_[8] = {(A0).x,(A0).y,(A0).z,(A0).w,                        \
                          (A1).x,(A1).y,(A1).z,(A1).w};                       \
    _Pragma("unroll")                                                         \
    for (int i2 = 0; i2 < 4; ++i2) {                                          \
        const unsigned w = cvt_pk_bf16(kv_[2*i2], kv_[2*i2+1]);               \
        (KD)[kwadr[2*i2]]   = (short)(w & 0xFFFFu);                           \
        (KD)[kwadr[2*i2+1]] = (short)(w >> 16);                               \
    }                                                                         \
    uint4 vw_;                                                                \
    vw_.x = cvt_pk_bf16((B0).x, (B0).y);                                      \
    vw_.y = cvt_pk_bf16((B0).z, (B0).w);                                      \
    vw_.z = cvt_pk_bf16((B1).x, (B1).y);                                      \
    vw_.w = cvt_pk_bf16((B1).z, (B1).w);                                      \
    *(uint4*)&(VD)[vwadr] = vw_;                                              \
} while (0)

// One block = 8 waves = 512 threads: one (head-batch, 128-row Q tile).
// == EXACT r11: the measured-best kernel of the session (92.1 us) ==
// Cross-tile software pipeline: each barrier window runs
//   {QK+softmax(tile s+1) || PV(tile s) || stage(tile s+2)}
// so ds_read-K latency + QK MFMAs + exp chain hide under PV's independent
// MFMAs.  K double-buffered, V TRIPLE-buffered (PV lags the writer by 2
// windows); 1 barrier/window; 15-step loop fully unrolled (static parity
// indices).  Swapped QK^T + kperm'd fragment-major K -> P entirely in
// registers; bfold'd block placement -> conflict-free fragment reads;
// packed-bit mask (1 u64/lane/window); exp2 softmax with pre-scaled Q and
// bias-in-C-init; ones-MFMA row sums; double-XOR-swizzled fp32 epilogue.
// Neighborhood exhausted: r4/r5/r10/r12/r13/r14 all regress (15-80%) by
// perturbing wave count, prefetch distance, or VMEM coherence.
// launch_bounds 2nd arg = workgroups/CU on this toolchain: (512,2) -> 128
// VGPR cap (60 used).  Spill tripwire: FETCH_SIZE ballooning (r2).
template<bool PM>
__global__ __launch_bounds__(512, 2)
void qkv_attn_kernel(const float* __restrict__ qkv,
                     const int* __restrict__ mask,
                     const u64* __restrict__ pm,
                     const float* __restrict__ qk_bias,
                     float* __restrict__ out)
{
    // 41600 B = 5 buffers x 4160 shorts: K0|K1|V0|V1|V2 (tile i -> K[i&1], V[i%3]).
    // prologue: shorts 0..8191 = Q [128][LSTR] swizzled (overlaps K0|K1).
    // epilogue: Os fp32 [128][64] = 32 KB (overlaps K0..V1).
    __shared__ __align__(16) char smem[5 * VOFF * 2];
    short* Qs = (short*)smem;
    short* const Kb[2] = { Qs,            Qs + VOFF };
    short* const Vb[3] = { Qs + 2 * VOFF, Qs + 3 * VOFF, Qs + 4 * VOFF };
    float* Os = (float*)smem;

    const int tid  = threadIdx.x;
    const int wave = tid >> 6;
    const int lane = tid & 63;
    const int quad = lane >> 4;
    const int l16  = lane & 15;

    const int bh    = blockIdx.x;   // 0..127: consecutive bh -> XCD round-robin
    const int qtile = blockIdx.y;   // 0..7:  stride-128 ids keep a bh on ONE XCD
    const int b     = bh >> 4;
    const int h     = bh & 15;
    const int t0    = qtile * 128;

    const size_t qbase = ((size_t)b * (3 * NH * CH) + (size_t)h * (3 * CH)) * T_LEN;
    const float* kp = qkv + qbase + (size_t)CH * T_LEN;
    const float* vp = qkv + qbase + (size_t)(2 * CH) * T_LEN;

    const float b_l2e  = qk_bias[0] * 1.44269504088896f;  // exp(x)=exp2(x*log2e)
    const float qscale = 0.125f * 1.44269504088896f;      // folded into Q staging

    const int c64 = tid >> 3;          // 0..63 channel row
    const int sse = (tid & 7) * 8;     // 8-s segment per thread (K/V staging)
    const int tse = (tid & 7) * 16;    // Q staging segment

    const float* kpr = kp + (size_t)c64 * T_LEN + sse;
    const float* vpr = vp + (size_t)c64 * T_LEN + sse;

    // fragment-read base (shorts): folded block of this lane, 16B-aligned
    const int bsl8 = bfold(lane) * 8;

    // ---- loop-invariant staging write addresses (fragment-major, folded) ----
    const int hk = c64 >> 5, qk = (c64 >> 3) & 3, coff = c64 & 7;
    int kwadr[8];
    #pragma unroll
    for (int j = 0; j < 8; ++j) {
        const int sp = kperm(sse + j);
        const int fk = (sp >> 4) * 2 + hk;
        const int bi = qk * 16 + (sp & 15);
        kwadr[j] = fk * FSTR + bfold(bi) * 8 + coff;
    }
    const int vwadr = ((c64 >> 4) * 2 + (sse >> 5)) * FSTR
                    + bfold(((sse >> 3) & 3) * 16 + (c64 & 15)) * 8;

    const int tl = t0 + wave * 16 + l16;   // lane's own t (mask row)
    const u64* pmb = PM ? pm + ((size_t)(h & 7) * T_LEN + tl) * (T_LEN / 64) : nullptr;
    const int* mrow = mask + (size_t)(h & 7) * T_LEN * T_LEN + (size_t)tl * T_LEN;

    // ---- prefetch tiles 0 and 1 + mask words ----
    float4 kf0 = *(const float4*)(kpr);
    float4 kf1 = *(const float4*)(kpr + 4);
    float4 vf0 = *(const float4*)(vpr);
    float4 vf1 = *(const float4*)(vpr + 4);
    float4 kg0 = *(const float4*)(kpr + 64);
    float4 kg1 = *(const float4*)(kpr + 68);
    float4 vg0 = *(const float4*)(vpr + 64);
    float4 vg1 = *(const float4*)(vpr + 68);
    u64 m0     = PM ? pmb[0] : 0ULL;
    u64 m_next = PM ? pmb[1] : 0ULL;

    // ---- stage Q transposed + swizzled + PRE-SCALED (shorts 0..8191) ----
    {
        const float* src = qkv + qbase + (size_t)c64 * T_LEN + t0 + tse;
        #pragma unroll
        for (int k = 0; k < 4; ++k) {
            float4 f = *(const float4*)(src + 4 * k);
            const int t = tse + 4 * k;
            Qs[(t + 0) * LSTR + (c64 ^ fsw(t + 0))] = f2bf(f.x * qscale);
            Qs[(t + 1) * LSTR + (c64 ^ fsw(t + 1))] = f2bf(f.y * qscale);
            Qs[(t + 2) * LSTR + (c64 ^ fsw(t + 2))] = f2bf(f.z * qscale);
            Qs[(t + 3) * LSTR + (c64 ^ fsw(t + 3))] = f2bf(f.w * qscale);
        }
    }
    __syncthreads();

    // ---- loop-invariant Q fragments (B-operand of swapped QK^T) ----
    const int qrow = wave * 16 + l16;
    const short8 aq0 = *(const short8*)&Qs[qrow * LSTR + ((quad * 8)      ^ fsw(qrow))];
    const short8 aq1 = *(const short8*)&Qs[qrow * LSTR + ((quad * 8 + 32) ^ fsw(qrow))];
    __syncthreads();   // Q region reused by K0/K1 below

    // ---- stage tiles 0,1 into K0/V0, K1/V1 ----
    KV_WRITE(Kb[0], Vb[0], kf0, kf1, vf0, vf1);
    KV_WRITE(Kb[1], Vb[1], kg0, kg1, vg0, vg1);
    __syncthreads();

    const short one_bf = (short)0x3F80;
    const short8 ones8 = (short8){one_bf, one_bf, one_bf, one_bf,
                                  one_bf, one_bf, one_bf, one_bf};

    floatx4 o[4], ol;
    #pragma unroll
    for (int i = 0; i < 4; ++i) o[i] = (floatx4){0.f, 0.f, 0.f, 0.f};
    ol = (floatx4){0.f, 0.f, 0.f, 0.f};

    // ---- pipeline prime: QK(0) -> pa[0]; barrier before window 0 writes K0 ----
    unsigned pa[2][8];
    QK_TILE(0, Kb[0], m0, pa[0]);
    __syncthreads();

    // ---- steady state: {QK(s+1) || PV(s) || stage(s+2)}; 1 barrier/step ----
    #pragma unroll
    for (int s = 0; s < 15; ++s) {
        if (s + 2 <= 15) {
            kf0 = *(const float4*)(kpr + (s + 2) * 64);
            kf1 = *(const float4*)(kpr + (s + 2) * 64 + 4);
            vf0 = *(const float4*)(vpr + (s + 2) * 64);
            vf1 = *(const float4*)(vpr + (s + 2) * 64 + 4);
        }
        const u64 m_use = m_next;                  // mask for tile s+1
        if (PM && s + 2 <= 15) m_next = pmb[s + 2];

        QK_TILE(s + 1, Kb[(s + 1) & 1], m_use, pa[(s + 1) & 1]);
        PV_TILE(Vb[s % 3], pa[s & 1]);

        if (s + 2 <= 15)
            KV_WRITE(Kb[s & 1], Vb[(s + 2) % 3], kf0, kf1, vf0, vf1);
        __syncthreads();
    }
    PV_TILE(Vb[15 % 3], pa[15 & 1]);               // drain: PV(15)

    // ---- epilogue: Os fp32 [128][64] (32 KB); double-XOR swizzle ----
    __syncthreads();   // all compute done before Os overwrites K/V buffers
    float inv[4];
    #pragma unroll
    for (int r = 0; r < 4; ++r) inv[r] = (ol[r] > 0.f) ? 1.f / ol[r] : 0.f;
    const int okeyw = (wave << 3) ^ (quad << 4);
    #pragma unroll
    for (int csub = 0; csub < 4; ++csub)
        #pragma unroll
        for (int r = 0; r < 4; ++r)
            Os[(wave * 16 + quad * 4 + r) * 64 + ((csub * 16 + l16) ^ okeyw)] =
                o[csub][r] * inv[r];
    __syncthreads();
    {
        float* dst = out + ((size_t)b * (NH * CH) + (size_t)h * CH + c64) * T_LEN
                   + t0 + tse;
        #pragma unroll
        for (int k = 0; k < 4; ++k) {
            float4 f;
            #pragma unroll
            for (int j = 0; j < 4; ++j) {
                const int rl = tse + 4 * k + j;
                const int ok = ((rl >> 4) << 3) ^ (((rl >> 2) & 3) << 4);
                ((float*)&f)[j] = Os[rl * 64 + (c64 ^ ok)];
            }
            *(float4*)(dst + 4 * k) = f;
        }
    }
}

extern "C" void kernel_launch(void* const* d_in, const int* in_sizes, int n_in,
                              void* d_out, int out_size, void* d_ws, size_t ws_size,
                              hipStream_t stream) {
    const float* qkv     = (const float*)d_in[0];
    const int*   mask    = (const int*)d_in[1];
    const float* qk_bias = (const float*)d_in[2];
    float*       out     = (float*)d_out;

    const size_t pm_bytes = (size_t)8 * T_LEN * (T_LEN / 64) * sizeof(u64);  // 1 MiB
    u64* pm = nullptr;
    if (d_ws && ws_size >= pm_bytes) {
        pm = (u64*)d_ws;
        pack_mask_kernel<<<2048, 256, 0, stream>>>(mask, pm);
    }

    dim3 grid(8 * NH, T_LEN / 128);  // (head-batches, q-tiles) = (128, 8)
    if (pm) qkv_attn_kernel<true ><<<grid, 512, 0, stream>>>(qkv, mask, pm, qk_bias, out);
    else    qkv_attn_kernel<false><<<grid, 512, 0, stream>>>(qkv, mask, nullptr, qk_bias, out);
}